// Round 10
// baseline (121.935 us; speedup 1.0000x reference)
//
#include <hip/hip_runtime.h>
#include <math.h>

// EUNN layer, H=1024: 16 steps of (even + odd) pairwise complex rotations + final phase.
// v14 = v10 (packed v_pk math, R=2, global transposed coeff table, no barriers)
// + FORCED register-resident coeff prefetch (v4's schedule, pinned with asm).
// Post-mortem chain: every shared-resource theory is dead (v7/v12 coeff path,
// v5/v13 TLP, v9 ILP, v6 NT). Accounting that closes: dur*VALUBusy == per-wave
// VALU issue demand across ALL variants -> duration is pinned by exposed per-wave
// load latency. VGPR history is the mechanism: v4 scalar had VGPR=124 (E/O
// prefetch register-resident, VALUBusy 41%); all packed variants have VGPR 60-68
// -> allocator SANK the coeff loads to uses (packed math freed temporaries, so
// minimal-liveness schedule won), exposing ~8 serialized 200-300cyc load-use
// round-trips per step = the observed ~6.3K cyc/step wall. Fix: v4's schedule
// (O loads at step top, covered by even compute; next-E loads after even,
// covered by odd) with asm "+v" pins that (a) force the waitcnt at a covered
// point, (b) make the value un-rematerializable so it stays in registers.
// launch_bounds(256,1): allocator free (~130-150 VGPR), grid gives 2 waves/SIMD.
//
// ws layout (f4 units): coeff_t[s][phase][512], slot k = (j&7)*64 + (j>>3) for pair j
//   (phase 0 = even pairs 0..511; phase 1 = odd pairs 0..510 + identity pad 511)
// omega (f4 = 2 elements (c,s,c,s)) transposed the same way at float offset 65536.

typedef float f4 __attribute__((ext_vector_type(4)));
typedef float f2 __attribute__((ext_vector_type(2)));

#define OMCS_OFF 65536

// ---- packed-f32 rotation primitives (c = (lo,hi) coefficient pair) ----
// T = c.lo*A - c.hi*B   (per half: A/B halves travel together)
__device__ __forceinline__ f2 rot_t(f2 c, f2 A, f2 B) {
  f2 m, t;
  asm("v_pk_mul_f32 %0, %1, %2 op_sel:[1,0] op_sel_hi:[1,1]"
      : "=v"(m) : "v"(c), "v"(B));                      // (hi*B.lo, hi*B.hi)
  asm("v_pk_fma_f32 %0, %1, %2, %3 op_sel:[0,0,0] op_sel_hi:[0,1,1] "
      "neg_lo:[0,0,1] neg_hi:[0,0,1]"
      : "=v"(t) : "v"(c), "v"(A), "v"(m));              // (lo*A.lo-m.lo, lo*A.hi-m.hi)
  return t;
}
// D = (c.hi*T.lo - c.lo*T.hi, c.lo*T.lo + c.hi*T.hi)   [c=(cp,sp), T=(t0,t1)]
__device__ __forceinline__ f2 rot_d(f2 c, f2 T) {
  f2 a, d;
  asm("v_pk_mul_f32 %0, %1, %2 op_sel:[1,0] op_sel_hi:[0,0]"
      : "=v"(a) : "v"(c), "v"(T));                      // (sp*t0, cp*t0)
  asm("v_pk_fma_f32 %0, %1, %2, %3 op_sel:[0,1,0] op_sel_hi:[1,1,1] "
      "neg_lo:[1,0,0] neg_hi:[0,0,0]"
      : "=v"(d) : "v"(c), "v"(T), "v"(a));              // (-cp*t1+a.lo, sp*t1+a.hi)
  return d;
}
// O = c.hi*A + c.lo*B
__device__ __forceinline__ f2 rot_o(f2 c, f2 A, f2 B) {
  f2 m, o;
  asm("v_pk_mul_f32 %0, %1, %2 op_sel:[0,0] op_sel_hi:[0,1]"
      : "=v"(m) : "v"(c), "v"(B));                      // (lo*B.lo, lo*B.hi)
  asm("v_pk_fma_f32 %0, %1, %2, %3 op_sel:[1,0,0] op_sel_hi:[1,1,1]"
      : "=v"(o) : "v"(c), "v"(A), "v"(m));              // (hi*A.lo+m.lo, hi*A.hi+m.hi)
  return o;
}
// complex multiply V*(W.lo + i W.hi): (W.lo*V.lo - W.hi*V.hi, W.hi*V.lo + W.lo*V.hi)
__device__ __forceinline__ f2 cmulp(f2 W, f2 V) {
  f2 m, o;
  asm("v_pk_mul_f32 %0, %1, %2 op_sel:[1,1] op_sel_hi:[1,0]"
      : "=v"(m) : "v"(W), "v"(V));                      // (s*vi, s*vr)
  asm("v_pk_fma_f32 %0, %1, %2, %3 op_sel:[0,0,0] op_sel_hi:[0,1,1] "
      "neg_lo:[0,0,1] neg_hi:[0,0,0]"
      : "=v"(o) : "v"(W), "v"(V), "v"(m));              // (c*vr-m.lo, c*vi+m.hi)
  return o;
}

__global__ __launch_bounds__(256) void eunn_precompute(
    const float* __restrict__ omega, const float* __restrict__ et,
    const float* __restrict__ ot, const float* __restrict__ ep,
    const float* __restrict__ op, float* __restrict__ ws) {
  int tid = blockIdx.x * 256 + threadIdx.x;
  if (tid < 16384) {
    int s = tid >> 10, k = tid & 1023;
    int phase = k >> 9, j = k & 511;
    float ct, st, cp, sp;
    if (phase == 0) {
      sincosf(et[s * 512 + j], &st, &ct);
      sincosf(ep[s * 512 + j], &sp, &cp);
    } else if (j < 511) {
      sincosf(ot[s * 511 + j], &st, &ct);
      sincosf(op[s * 511 + j], &sp, &cp);
    } else {  // identity pad pair (elements 1023/1024)
      ct = 1.f; st = 0.f; cp = 0.f; sp = 1.f;
    }
    // transposed slot: lane = j>>3 owns pair j as its (j&7)-th register
    ((f4*)ws)[s * 1024 + phase * 512 + (j & 7) * 64 + (j >> 3)] =
        (f4){ct, st, cp, sp};
  } else if (tid < 16896) {
    int m = tid - 16384;  // f4 index covering elements 2m, 2m+1
    float s0, c0, s1, c1;
    sincosf(omega[2 * m], &s0, &c0);
    sincosf(omega[2 * m + 1], &s1, &c1);
    ((f4*)(ws + OMCS_OFF))[(m & 7) * 64 + (m >> 3)] = (f4){c0, s0, c1, s1};
  }
}

// One wave owns R rows; lane l owns elements 16l..16l+15 (8 even pairs).
// ea[r][p] = complex element 16l+2p, eb[r][p] = complex element 16l+2p+1 (f2 pairs).
// Pipeline (v4 schedule, pinned): O[s] issued at step top (completion forced by
// pin after even rot); E[s+1] issued after even rot (completion forced by pin
// after odd rot); both held in registers across the covering compute phase.
template <int R>
__global__ __launch_bounds__(256, 1) void eunn_main(
    const float* __restrict__ x, float* __restrict__ out,
    const float* __restrict__ ws) {
  const int lane = threadIdx.x & 63;
  const int wid = blockIdx.x * (blockDim.x >> 6) + (threadIdx.x >> 6);
  const f4* cf = (const f4*)ws + lane;  // + p*64 + s*1024 (+512 for odd)

  f2 ea[R][8], eb[R][8];
#pragma unroll
  for (int r = 0; r < R; ++r) {
    const f4* xr = (const f4*)(x + (size_t)(wid * R + r) * 2048) + lane * 8;
#pragma unroll
    for (int p = 0; p < 8; ++p) {
      f4 t = xr[p];
      ea[r][p] = (f2){t.x, t.y};
      eb[r][p] = (f2){t.z, t.w};
    }
  }

  f4 E[8], En[8], O[8];
#pragma unroll
  for (int p = 0; p < 8; ++p) E[p] = cf[p * 64];  // step 0 even coeffs

#pragma unroll 1
  for (int s = 0; s < 16; ++s) {
    // ---- issue this step's odd coeff loads (covered by even compute) ----
    {
      const f4* ob = cf + s * 1024 + 512;
#pragma unroll
      for (int p = 0; p < 8; ++p) O[p] = ob[p * 64];
    }
    // ---- even rotation: pair j=8l+p couples ea[p] and eb[p] ----
#pragma unroll
    for (int r = 0; r < R; ++r) {
#pragma unroll
      for (int p = 0; p < 8; ++p) {
        f2 cxy = (f2){E[p].x, E[p].y};   // (ct, st)
        f2 czw = (f2){E[p].z, E[p].w};   // (cp, sp)
        f2 a = ea[r][p], b = eb[r][p];
        f2 T = rot_t(cxy, a, b);         // ct*a - st*b
        ea[r][p] = rot_d(czw, T);        // (sp*t0-cp*t1, cp*t0+sp*t1)
        eb[r][p] = rot_o(cxy, a, b);     // st*a + ct*b
      }
    }
    // ---- pin O: forces completion here (covered by even) + register residency ----
    asm volatile("" : "+v"(O[0]), "+v"(O[1]), "+v"(O[2]), "+v"(O[3]),
                      "+v"(O[4]), "+v"(O[5]), "+v"(O[6]), "+v"(O[7]));

    // ---- issue next step's even coeff loads (covered by odd compute) ----
    {
      const f4* nb = cf + ((s + 1) & 15) * 1024;
#pragma unroll
      for (int p = 0; p < 8; ++p) En[p] = nb[p * 64];
    }

    // ---- odd rotation: pair j couples elements 2j+1, 2j+2 ----
    {
      // neighbor pair (8l-1)'s (ct,st) from lane l-1; identity at lane 0
      float ctm = __shfl_up(O[7].x, 1, 64);
      float stm = __shfl_up(O[7].y, 1, 64);
      if (lane == 0) { ctm = 1.f; stm = 0.f; }
      f2 cm2 = (f2){ctm, stm};
#pragma unroll
      for (int r = 0; r < R; ++r) {
        float upx = __shfl_down(ea[r][0].x, 1, 64);  // elem 16l+16 (pre)
        float upy = __shfl_down(ea[r][0].y, 1, 64);
        float dnz = __shfl_up(eb[r][7].x, 1, 64);    // elem 16l-1 (pre)
        float dnw = __shfl_up(eb[r][7].y, 1, 64);
        // element 16l = second half of pair 8l-1: stm*D + ctm*X
        f2 D = (f2){dnz, dnw};
        ea[r][0] = rot_o(cm2, D, ea[r][0]);
        // interior odd pairs j=8l+p, p=0..6: couples eb[p] and ea[p+1]
#pragma unroll
        for (int p = 0; p < 7; ++p) {
          f2 oxy = (f2){O[p].x, O[p].y};
          f2 ozw = (f2){O[p].z, O[p].w};
          f2 A = eb[r][p], B = ea[r][p + 1];
          f2 T = rot_t(oxy, A, B);
          eb[r][p] = rot_d(ozw, T);
          ea[r][p + 1] = rot_o(oxy, A, B);
        }
        // boundary pair j=8l+7 (second element lives in lane l+1; lane 63 = identity)
        {
          f2 oxy = (f2){O[7].x, O[7].y};
          f2 ozw = (f2){O[7].z, O[7].w};
          f2 UP = (f2){upx, upy};
          f2 T = rot_t(oxy, eb[r][7], UP);
          eb[r][7] = rot_d(ozw, T);
        }
      }
    }

    // ---- pin En: forces completion here (covered by odd) + register residency ----
    asm volatile("" : "+v"(En[0]), "+v"(En[1]), "+v"(En[2]), "+v"(En[3]),
                      "+v"(En[4]), "+v"(En[5]), "+v"(En[6]), "+v"(En[7]));
#pragma unroll
    for (int p = 0; p < 8; ++p) E[p] = En[p];
  }

  // ---- final diagonal phase + store ----
  const f4* om4 = (const f4*)(ws + OMCS_OFF) + lane;  // (c,s,c,s), + p*64
#pragma unroll
  for (int r = 0; r < R; ++r) {
    f4* outr = (f4*)(out + (size_t)(wid * R + r) * 2048) + lane * 8;
#pragma unroll
    for (int p = 0; p < 8; ++p) {
      f4 w = om4[p * 64];
      f2 o1 = cmulp((f2){w.x, w.y}, ea[r][p]);
      f2 o2 = cmulp((f2){w.z, w.w}, eb[r][p]);
      outr[p] = (f4){o1.x, o1.y, o2.x, o2.y};
    }
  }
}

extern "C" void kernel_launch(void* const* d_in, const int* in_sizes, int n_in,
                              void* d_out, int out_size, void* d_ws, size_t ws_size,
                              hipStream_t stream) {
  const float* x     = (const float*)d_in[0];  // (4096,1024,2)
  const float* omega = (const float*)d_in[1];  // (1024,)
  const float* et    = (const float*)d_in[2];  // (16,512)
  const float* ot    = (const float*)d_in[3];  // (16,511)
  const float* ep    = (const float*)d_in[4];  // (16,512)
  const float* op    = (const float*)d_in[5];  // (16,511)
  float* out = (float*)d_out;
  float* ws  = (float*)d_ws;

  // 16896 jobs: 16x1024 coeff quads + 512 omega f4 entries
  eunn_precompute<<<dim3(66), dim3(256), 0, stream>>>(omega, et, ot, ep, op, ws);

  // R=2 rows/wave: 2048 waves, 4 waves/block -> 512 blocks (2/CU, 8 waves/CU)
  eunn_main<2><<<dim3(512), dim3(256), 0, stream>>>(x, out, ws);
}